// Round 1
// baseline (743.382 us; speedup 1.0000x reference)
//
#include <hip/hip_runtime.h>
#include <cstdint>

typedef unsigned short ushort_t;
typedef __attribute__((ext_vector_type(8))) __bf16 bf16x8;
typedef __attribute__((ext_vector_type(4))) float f32x4;
typedef __attribute__((ext_vector_type(8))) unsigned short ushort8;

constexpr int NB = 16;    // batch
constexpr int NC = 256;   // channels C
constexpr int NN = 4096;  // tokens N = H*W
constexpr int NP = 1024;  // region-proj channels = 2*R*heads
constexpr int NT = 512;   // heads * R (Rq columns of T)

static __device__ __forceinline__ ushort_t f2b(float f) {
  uint32_t u = __builtin_bit_cast(uint32_t, f);
  u += 0x7FFFu + ((u >> 16) & 1u);
  return (ushort_t)(u >> 16);
}
static __device__ __forceinline__ float b2f(ushort_t h) {
  return __builtin_bit_cast(float, (uint32_t)h << 16);
}
static __device__ __forceinline__ f32x4 mfma16(bf16x8 a, bf16x8 b, f32x4 c) {
  return __builtin_amdgcn_mfma_f32_16x16x32_bf16(a, b, c, 0, 0, 0);
}

// ---------------------------------------------------------------------------
// K1: r[b,p,n] = Wr[p,:]·x[b,:,n] + br[p]  -> P (bf16, pre-softmax)
// GEMM M=1024(p) N=4096(n) K=256(c), per-batch. 64x64 tile, BK=32, 4 waves.
// ---------------------------------------------------------------------------
__global__ __launch_bounds__(256) void k1_proj(const float* __restrict__ x,
                                               const float* __restrict__ Wr,
                                               const float* __restrict__ br,
                                               ushort_t* __restrict__ P) {
  __shared__ __align__(16) ushort_t As[64][40];
  __shared__ __align__(16) ushort_t Bs[64][40];
  const int tid = threadIdx.x;
  const int n0 = blockIdx.x * 64, m0 = blockIdx.y * 64, b = blockIdx.z;
  const int lane = tid & 63, w = tid >> 6;
  const int wm = (w >> 1) * 32, wn = (w & 1) * 32;
  const float* xb = x + (size_t)b * NC * NN;
  f32x4 acc[2][2] = {};
  const int arow = tid >> 2, akk = (tid & 3) * 8;   // A stage: 64 rows x 32 k
  const int bkk = tid >> 3, bnn = (tid & 7) * 8;    // B stage: 32 k x 64 n

  for (int k0 = 0; k0 < NC; k0 += 32) {
    {  // A = Wr rows (k=c contiguous)
      const float* s = Wr + (size_t)(m0 + arow) * NC + k0 + akk;
      float4 v0 = *(const float4*)s, v1 = *(const float4*)(s + 4);
      ushort_t* d = &As[arow][akk];
      d[0] = f2b(v0.x); d[1] = f2b(v0.y); d[2] = f2b(v0.z); d[3] = f2b(v0.w);
      d[4] = f2b(v1.x); d[5] = f2b(v1.y); d[6] = f2b(v1.z); d[7] = f2b(v1.w);
    }
    {  // B = x (rows n-contiguous) transpose-staged to Bs[n_local][k]
      const float* s = xb + (size_t)(k0 + bkk) * NN + n0 + bnn;
      float4 v0 = *(const float4*)s, v1 = *(const float4*)(s + 4);
      Bs[bnn + 0][bkk] = f2b(v0.x); Bs[bnn + 1][bkk] = f2b(v0.y);
      Bs[bnn + 2][bkk] = f2b(v0.z); Bs[bnn + 3][bkk] = f2b(v0.w);
      Bs[bnn + 4][bkk] = f2b(v1.x); Bs[bnn + 5][bkk] = f2b(v1.y);
      Bs[bnn + 6][bkk] = f2b(v1.z); Bs[bnn + 7][bkk] = f2b(v1.w);
    }
    __syncthreads();
    const int fr = lane & 15, kq = (lane >> 4) * 8;
    bf16x8 a0 = *(const bf16x8*)&As[wm + fr][kq];
    bf16x8 a1 = *(const bf16x8*)&As[wm + 16 + fr][kq];
    bf16x8 b0 = *(const bf16x8*)&Bs[wn + fr][kq];
    bf16x8 b1 = *(const bf16x8*)&Bs[wn + 16 + fr][kq];
    acc[0][0] = mfma16(a0, b0, acc[0][0]);
    acc[0][1] = mfma16(a0, b1, acc[0][1]);
    acc[1][0] = mfma16(a1, b0, acc[1][0]);
    acc[1][1] = mfma16(a1, b1, acc[1][1]);
    __syncthreads();
  }
  const int col = lane & 15, rb = (lane >> 4) * 4;
#pragma unroll
  for (int fm = 0; fm < 2; fm++)
#pragma unroll
    for (int fn = 0; fn < 2; fn++)
#pragma unroll
      for (int rg = 0; rg < 4; rg++) {
        int row = m0 + wm + fm * 16 + rb + rg;
        int cc = n0 + wn + fn * 16 + col;
        P[((size_t)b * NP + row) * NN + cc] = f2b(acc[fm][fn][rg] + br[row]);
      }
}

// ---------------------------------------------------------------------------
// K2: in-place softmax over the 1024 channel axis, per (b,n) column.
// ---------------------------------------------------------------------------
__global__ __launch_bounds__(256) void k2_softmax(ushort_t* __restrict__ P) {
  const int n = blockIdx.x * 256 + threadIdx.x;
  const int b = blockIdx.y;
  ushort_t* colp = P + (size_t)b * NP * NN + n;
  float m = -3.0e38f, s = 0.0f;
#pragma unroll 4
  for (int p = 0; p < NP; p++) {
    float v = b2f(colp[(size_t)p * NN]);
    float mn = fmaxf(m, v);
    s = s * __expf(m - mn) + __expf(v - mn);
    m = mn;
  }
  const float inv = 1.0f / s;
#pragma unroll 4
  for (int p = 0; p < NP; p++) {
    size_t i = (size_t)p * NN;
    colp[i] = f2b(__expf(b2f(colp[i]) - m) * inv);
  }
}

// ---------------------------------------------------------------------------
// K2b: sP[b,p] = sum_n P[b,p,n]  (needed for the pooled bias terms)
// ---------------------------------------------------------------------------
__global__ __launch_bounds__(256) void k2b_rowsum(const ushort_t* __restrict__ P,
                                                  float* __restrict__ sP) {
  const int row = blockIdx.x * 4 + (threadIdx.x >> 6);
  const int lane = threadIdx.x & 63;
  const ushort_t* src = P + (size_t)row * NN;
  float s = 0.f;
#pragma unroll
  for (int it = 0; it < 8; it++) {
    ushort8 v = *(const ushort8*)(src + (size_t)(it * 64 + lane) * 8);
#pragma unroll
    for (int j = 0; j < 8; j++) s += b2f(v[j]);
  }
  for (int off = 32; off > 0; off >>= 1) s += __shfl_down(s, off, 64);
  if (lane == 0) sP[row] = s;
}

// ---------------------------------------------------------------------------
// K3: XR[b,c,p] = sum_n x[b,c,n] * P[b,p,n]   (NT GEMM, K=4096)
// M=256(c) N=1024(p) K=4096(n). Both operands k-contiguous: direct staging.
// ---------------------------------------------------------------------------
__global__ __launch_bounds__(256) void k3_pool(const float* __restrict__ x,
                                               const ushort_t* __restrict__ P,
                                               float* __restrict__ XR) {
  __shared__ __align__(16) ushort_t As[64][40];
  __shared__ __align__(16) ushort_t Bs[64][40];
  const int tid = threadIdx.x;
  const int n0 = blockIdx.x * 64;  // p
  const int m0 = blockIdx.y * 64;  // c
  const int b = blockIdx.z;
  const int lane = tid & 63, w = tid >> 6;
  const int wm = (w >> 1) * 32, wn = (w & 1) * 32;
  f32x4 acc[2][2] = {};
  const int arow = tid >> 2, akk = (tid & 3) * 8;

  for (int k0 = 0; k0 < NN; k0 += 32) {
    {  // A = x rows (c), k=n contiguous
      const float* s = x + ((size_t)b * NC + m0 + arow) * NN + k0 + akk;
      float4 v0 = *(const float4*)s, v1 = *(const float4*)(s + 4);
      ushort_t* d = &As[arow][akk];
      d[0] = f2b(v0.x); d[1] = f2b(v0.y); d[2] = f2b(v0.z); d[3] = f2b(v0.w);
      d[4] = f2b(v1.x); d[5] = f2b(v1.y); d[6] = f2b(v1.z); d[7] = f2b(v1.w);
    }
    {  // B = P rows (p), k=n contiguous, already bf16
      const ushort_t* s = P + ((size_t)b * NP + n0 + arow) * NN + k0 + akk;
      *(ushort8*)&Bs[arow][akk] = *(const ushort8*)s;
    }
    __syncthreads();
    const int fr = lane & 15, kq = (lane >> 4) * 8;
    bf16x8 a0 = *(const bf16x8*)&As[wm + fr][kq];
    bf16x8 a1 = *(const bf16x8*)&As[wm + 16 + fr][kq];
    bf16x8 b0 = *(const bf16x8*)&Bs[wn + fr][kq];
    bf16x8 b1 = *(const bf16x8*)&Bs[wn + 16 + fr][kq];
    acc[0][0] = mfma16(a0, b0, acc[0][0]);
    acc[0][1] = mfma16(a0, b1, acc[0][1]);
    acc[1][0] = mfma16(a1, b0, acc[1][0]);
    acc[1][1] = mfma16(a1, b1, acc[1][1]);
    __syncthreads();
  }
  const int col = lane & 15, rb = (lane >> 4) * 4;
#pragma unroll
  for (int fm = 0; fm < 2; fm++)
#pragma unroll
    for (int fn = 0; fn < 2; fn++)
#pragma unroll
      for (int rg = 0; rg < 4; rg++) {
        int row = m0 + wm + fm * 16 + rb + rg;  // c
        int cc = n0 + wn + fn * 16 + col;       // p
        XR[((size_t)b * NC + row) * NP + cc] = acc[fm][fn][rg];
      }
}

// ---------------------------------------------------------------------------
// K4: per-(b,h) tiny attention. qr/kr/vr = Wqkv_h·XR + bias·colsum; logits;
// softmax; vals; then fold Wout: T[b,c,h*64+j] = sum_d Wout[c,h*32+d]·vals[d,j]
// ---------------------------------------------------------------------------
__global__ __launch_bounds__(256) void k4_attn(const float* __restrict__ XR,
                                               const float* __restrict__ sP,
                                               const float* __restrict__ Wqkv,
                                               const float* __restrict__ bqkv,
                                               const float* __restrict__ Wout,
                                               float* __restrict__ Tm) {
  const int bh = blockIdx.x;
  const int b = bh >> 3, h = bh & 7;
  const int tid = threadIdx.x;
  __shared__ float Ws[96][64];       // Wqkv head-slice, c-chunk
  __shared__ float XRs[64][128];     // XR c-chunk x 128 region cols
  __shared__ float qf[96][64];       // qr(0:32) kr(32:64) vr(64:96)
  __shared__ float attn_sT[64][65];  // [k][q], padded
  __shared__ float vals_s[32][64];
  __shared__ float sPq_s[64], sPk_s[64];

  if (tid < 64) sPq_s[tid] = sP[(size_t)b * NP + h * 128 + tid];
  else if (tid < 128) sPk_s[tid - 64] = sP[(size_t)b * NP + h * 128 + tid];

  float acc1[24];
#pragma unroll
  for (int r = 0; r < 24; r++) acc1[r] = 0.f;

  for (int c0 = 0; c0 < NC; c0 += 64) {
    __syncthreads();
    for (int u = tid; u < 96 * 64; u += 256) {
      int rw = u >> 6, cc = u & 63;
      Ws[rw][cc] = Wqkv[(size_t)(h * 96 + rw) * NC + c0 + cc];
    }
    for (int u = tid; u < 64 * 128; u += 256) {
      int rw = u >> 7, cc = u & 127;
      XRs[rw][cc] = XR[((size_t)b * NC + c0 + rw) * NP + h * 128 + cc];
    }
    __syncthreads();
#pragma unroll
    for (int r = 0; r < 24; r++) {
      int idx = r * 256 + tid;
      int row = idx >> 6, j = idx & 63;
      int cb = (row < 32) ? 0 : 64;  // q pools with Rq, k/v with Rk
      float a = 0.f;
#pragma unroll 8
      for (int cc = 0; cc < 64; cc++) a += Ws[row][cc] * XRs[cc][cb + j];
      acc1[r] += a;
    }
  }
  __syncthreads();
#pragma unroll
  for (int r = 0; r < 24; r++) {
    int idx = r * 256 + tid;
    int row = idx >> 6, j = idx & 63;
    float bias = bqkv[h * 96 + row] * ((row < 32) ? sPq_s[j] : sPk_s[j]);
    qf[row][j] = acc1[r] + bias;
  }
  __syncthreads();
  // logits[q,k] = qr[:,q]·kr[:,k] / sqrt(32), stored transposed [k][q]
  const float isc = 0.17677669529663687f;
#pragma unroll
  for (int r = 0; r < 16; r++) {
    int o = r * 256 + tid;
    int qi = o >> 6, ki = o & 63;
    float a = 0.f;
#pragma unroll 8
    for (int dd = 0; dd < 32; dd++) a += qf[dd][qi] * qf[32 + dd][ki];
    attn_sT[ki][qi] = a * isc;
  }
  __syncthreads();
  if (tid < 64) {  // softmax over k for row q=tid
    float m = -3e38f;
    for (int k = 0; k < 64; k++) m = fmaxf(m, attn_sT[k][tid]);
    float s = 0.f;
    for (int k = 0; k < 64; k++) {
      float e = __expf(attn_sT[k][tid] - m);
      attn_sT[k][tid] = e;
      s += e;
    }
    float inv = 1.f / s;
    for (int k = 0; k < 64; k++) attn_sT[k][tid] *= inv;
  }
  __syncthreads();
  // vals[d,q] = sum_k vr[d,k] attn[q,k]
#pragma unroll
  for (int r = 0; r < 8; r++) {
    int o = r * 256 + tid;
    int dd = o >> 6, q = o & 63;
    float a = 0.f;
#pragma unroll 8
    for (int k = 0; k < 64; k++) a += qf[64 + dd][k] * attn_sT[k][q];
    vals_s[dd][q] = a;
  }
  __syncthreads();
  // T[c, h*64+j] = sum_d Wout[c, h*32+d] * vals[d,j]
  for (int r = 0; r < 64; r++) {
    int o = r * 256 + tid;
    int c = o >> 6, j = o & 63;
    float a = 0.f;
#pragma unroll 8
    for (int dd = 0; dd < 32; dd++)
      a += Wout[(size_t)c * NC + h * 32 + dd] * vals_s[dd][j];
    Tm[((size_t)b * NC + c) * NT + h * 64 + j] = a;
  }
}

// ---------------------------------------------------------------------------
// K5: out[b,c,n] = x + alpha*( sum_hj T[b,c,hj]·P[b,(hj>>6)*128+(hj&63),n] + bout[c] )
// GEMM M=256(c) N=4096(n) K=512(hj) + fused residual epilogue.
// ---------------------------------------------------------------------------
__global__ __launch_bounds__(256) void k5_out(const float* __restrict__ x,
                                              const ushort_t* __restrict__ P,
                                              const float* __restrict__ Tm,
                                              const float* __restrict__ bout,
                                              const float* __restrict__ alpha,
                                              float* __restrict__ out) {
  __shared__ __align__(16) ushort_t As[64][40];
  __shared__ __align__(16) ushort_t Bs[64][40];
  const int tid = threadIdx.x;
  const int n0 = blockIdx.x * 64, m0 = blockIdx.y * 64, b = blockIdx.z;
  const int lane = tid & 63, w = tid >> 6;
  const int wm = (w >> 1) * 32, wn = (w & 1) * 32;
  f32x4 acc[2][2] = {};
  const int arow = tid >> 2, akk = (tid & 3) * 8;
  const int bkk = tid >> 3, bnn = (tid & 7) * 8;

  for (int k0 = 0; k0 < NT; k0 += 32) {
    {  // A = T rows (k=hj contiguous)
      const float* s = Tm + ((size_t)b * NC + m0 + arow) * NT + k0 + akk;
      float4 v0 = *(const float4*)s, v1 = *(const float4*)(s + 4);
      ushort_t* d = &As[arow][akk];
      d[0] = f2b(v0.x); d[1] = f2b(v0.y); d[2] = f2b(v0.z); d[3] = f2b(v0.w);
      d[4] = f2b(v1.x); d[5] = f2b(v1.y); d[6] = f2b(v1.z); d[7] = f2b(v1.w);
    }
    {  // B = Rq-half of P, transpose-staged (rows n-contiguous)
      int hjj = k0 + bkk;
      int prow = ((hjj >> 6) << 7) + (hjj & 63);
      const ushort_t* s = P + ((size_t)b * NP + prow) * NN + n0 + bnn;
      ushort8 v = *(const ushort8*)s;
      Bs[bnn + 0][bkk] = v[0]; Bs[bnn + 1][bkk] = v[1];
      Bs[bnn + 2][bkk] = v[2]; Bs[bnn + 3][bkk] = v[3];
      Bs[bnn + 4][bkk] = v[4]; Bs[bnn + 5][bkk] = v[5];
      Bs[bnn + 6][bkk] = v[6]; Bs[bnn + 7][bkk] = v[7];
    }
    __syncthreads();
    const int fr = lane & 15, kq = (lane >> 4) * 8;
    bf16x8 a0 = *(const bf16x8*)&As[wm + fr][kq];
    bf16x8 a1 = *(const bf16x8*)&As[wm + 16 + fr][kq];
    bf16x8 b0 = *(const bf16x8*)&Bs[wn + fr][kq];
    bf16x8 b1 = *(const bf16x8*)&Bs[wn + 16 + fr][kq];
    acc[0][0] = mfma16(a0, b0, acc[0][0]);
    acc[0][1] = mfma16(a0, b1, acc[0][1]);
    acc[1][0] = mfma16(a1, b0, acc[1][0]);
    acc[1][1] = mfma16(a1, b1, acc[1][1]);
    __syncthreads();
  }
  const float al = alpha[0];
  const int col = lane & 15, rb = (lane >> 4) * 4;
#pragma unroll
  for (int fm = 0; fm < 2; fm++)
#pragma unroll
    for (int fn = 0; fn < 2; fn++)
#pragma unroll
      for (int rg = 0; rg < 4; rg++) {
        int row = m0 + wm + fm * 16 + rb + rg;  // c
        int cc = n0 + wn + fn * 16 + col;       // n
        size_t idx = ((size_t)b * NC + row) * NN + cc;
        out[idx] = x[idx] + al * (acc[fm][fn][rg] + bout[row]);
      }
}

// ---------------------------------------------------------------------------
extern "C" void kernel_launch(void* const* d_in, const int* in_sizes, int n_in,
                              void* d_out, int out_size, void* d_ws, size_t ws_size,
                              hipStream_t stream) {
  const float* x = (const float*)d_in[0];
  const float* Wqkv = (const float*)d_in[1];
  const float* bqkv = (const float*)d_in[2];
  const float* Wr = (const float*)d_in[3];
  const float* br = (const float*)d_in[4];
  const float* Wout = (const float*)d_in[5];
  const float* bout = (const float*)d_in[6];
  const float* alpha = (const float*)d_in[7];
  float* out = (float*)d_out;

  char* ws = (char*)d_ws;
  ushort_t* P = (ushort_t*)ws;                  // 16*1024*4096*2 = 134217728 B
  float* XR = (float*)(ws + 134217728);         // 16*256*1024*4  = 16777216 B
  float* sP = (float*)(ws + 150994944);         // 16*1024*4      = 65536 B
  float* Tm = (float*)(ws + 151060480);         // 16*256*512*4   = 8388608 B

  k1_proj<<<dim3(64, 16, 16), 256, 0, stream>>>(x, Wr, br, P);
  k2_softmax<<<dim3(16, 16), 256, 0, stream>>>(P);
  k2b_rowsum<<<dim3(4096), 256, 0, stream>>>(P, sP);
  k3_pool<<<dim3(16, 4, 16), 256, 0, stream>>>(x, P, XR);
  k4_attn<<<dim3(128), 256, 0, stream>>>(XR, sP, Wqkv, bqkv, Wout, Tm);
  k5_out<<<dim3(64, 4, 16), 256, 0, stream>>>(x, P, Tm, bout, alpha, out);
}

// Round 2
// 433.282 us; speedup vs baseline: 1.7157x; 1.7157x over previous
//
#include <hip/hip_runtime.h>
#include <cstdint>

typedef unsigned short ushort_t;
typedef __attribute__((ext_vector_type(4))) unsigned short ushort4_t;
typedef __attribute__((ext_vector_type(8))) unsigned short ushort8_t;
typedef __attribute__((ext_vector_type(8))) __bf16 bf16x8;
typedef __attribute__((ext_vector_type(4))) float f32x4;

constexpr int NB = 16;    // batch
constexpr int NC = 256;   // channels C (== E)
constexpr int NN = 4096;  // tokens N = H*W
constexpr int NP = 1024;  // region-proj channels = 2*R*heads
constexpr int NT = 512;   // heads * R (Rq columns of T)

static __device__ __forceinline__ ushort_t f2b(float f) {
  uint32_t u = __builtin_bit_cast(uint32_t, f);
  u += 0x7FFFu + ((u >> 16) & 1u);
  return (ushort_t)(u >> 16);
}
static __device__ __forceinline__ float b2f(ushort_t h) {
  return __builtin_bit_cast(float, (uint32_t)h << 16);
}
static __device__ __forceinline__ f32x4 mfma16(bf16x8 a, bf16x8 b, f32x4 c) {
  return __builtin_amdgcn_mfma_f32_16x16x32_bf16(a, b, c, 0, 0, 0);
}
typedef __attribute__((address_space(1))) const unsigned int guint;
typedef __attribute__((address_space(3))) unsigned int luint;
static __device__ __forceinline__ void glds16(const void* g, void* l) {
  __builtin_amdgcn_global_load_lds((guint*)g, (luint*)l, 16, 0, 0);
}

// ---------------------------------------------------------------------------
// K0: x (f32 [b][c][n]) -> xb (bf16 [b][c][n]) and xt (bf16 [b][n][c])
// ---------------------------------------------------------------------------
__global__ __launch_bounds__(256) void k0_cvt(const float* __restrict__ x,
                                              ushort_t* __restrict__ xb,
                                              ushort_t* __restrict__ xt) {
  __shared__ ushort_t tr[64][88];  // [n][c], padded, 16B-aligned rows
  const int tid = threadIdx.x;
  const int n0 = blockIdx.x * 64, c0 = blockIdx.y * 64, b = blockIdx.z;
  const int cr = (tid >> 4) * 4;   // 4 c-rows per thread
  const int nc4 = (tid & 15) * 4;  // 4 n-cols per thread
#pragma unroll
  for (int i = 0; i < 4; i++) {
    size_t idx = ((size_t)b * NC + c0 + cr + i) * NN + n0 + nc4;
    float4 v = *(const float4*)(x + idx);
    ushort4_t o;
    o[0] = f2b(v.x); o[1] = f2b(v.y); o[2] = f2b(v.z); o[3] = f2b(v.w);
    *(ushort4_t*)(xb + idx) = o;
    tr[nc4 + 0][cr + i] = o[0];
    tr[nc4 + 1][cr + i] = o[1];
    tr[nc4 + 2][cr + i] = o[2];
    tr[nc4 + 3][cr + i] = o[3];
  }
  __syncthreads();
  const int nr = tid >> 2, cc0 = (tid & 3) * 16;
  size_t odx = ((size_t)b * NN + n0 + nr) * NC + c0 + cc0;
  *(ushort8_t*)(xt + odx) = *(const ushort8_t*)&tr[nr][cc0];
  *(ushort8_t*)(xt + odx + 8) = *(const ushort8_t*)&tr[nr][cc0 + 8];
}

// K0b: Wr f32 -> bf16
__global__ __launch_bounds__(256) void k0b_wr(const float* __restrict__ Wr,
                                              ushort_t* __restrict__ Wrb) {
  int i = (blockIdx.x * 256 + threadIdx.x) * 4;
  float4 v = *(const float4*)(Wr + i);
  ushort4_t o;
  o[0] = f2b(v.x); o[1] = f2b(v.y); o[2] = f2b(v.z); o[3] = f2b(v.w);
  *(ushort4_t*)(Wrb + i) = o;
}

// ---------------------------------------------------------------------------
// K1: P[b,p,n] = Wrb[p,:]·xt[b,n,:] + br[p]  (pre-softmax, bf16 out)
// 128x128 tile, BK=32, glds both operands.
// ---------------------------------------------------------------------------
__global__ __launch_bounds__(256) void k1_proj(const ushort_t* __restrict__ Wrb,
                                               const ushort_t* __restrict__ xt,
                                               const float* __restrict__ br,
                                               ushort_t* __restrict__ P) {
  __shared__ __align__(16) ushort_t As[128 * 32];
  __shared__ __align__(16) ushort_t Bs[128 * 32];
  const int tid = threadIdx.x;
  const int n0 = blockIdx.x * 128, m0 = blockIdx.y * 128, b = blockIdx.z;
  const int lane = tid & 63, w = tid >> 6;
  const int wm = (w >> 1) * 64, wn = (w & 1) * 64;
  const int srow = tid >> 2, koff = (tid & 3) * 8;
  ushort_t* A0 = As + w * 512;
  ushort_t* A1 = As + 2048 + w * 512;
  ushort_t* B0 = Bs + w * 512;
  ushort_t* B1 = Bs + 2048 + w * 512;
  const ushort_t* Asrc = Wrb + (size_t)(m0 + srow) * NC + koff;
  const ushort_t* Bsrc = xt + ((size_t)b * NN + n0 + srow) * NC + koff;
  f32x4 acc[4][4] = {};
  const int fr = lane & 15, kq = (lane >> 4) * 8;
  for (int k0 = 0; k0 < NC; k0 += 32) {
    glds16(Asrc + k0, A0);
    glds16(Asrc + (size_t)64 * NC + k0, A1);
    glds16(Bsrc + k0, B0);
    glds16(Bsrc + (size_t)64 * NC + k0, B1);
    __syncthreads();
    bf16x8 af[4], bf[4];
#pragma unroll
    for (int f = 0; f < 4; f++) {
      af[f] = *(const bf16x8*)&As[(wm + f * 16 + fr) * 32 + kq];
      bf[f] = *(const bf16x8*)&Bs[(wn + f * 16 + fr) * 32 + kq];
    }
#pragma unroll
    for (int fm = 0; fm < 4; fm++)
#pragma unroll
      for (int fn = 0; fn < 4; fn++) acc[fm][fn] = mfma16(af[fm], bf[fn], acc[fm][fn]);
    __syncthreads();
  }
  const int col = lane & 15, rb = (lane >> 4) * 4;
#pragma unroll
  for (int fm = 0; fm < 4; fm++)
#pragma unroll
    for (int rg = 0; rg < 4; rg++) {
      int row = m0 + wm + fm * 16 + rb + rg;
      float bias = br[row];
#pragma unroll
      for (int fn = 0; fn < 4; fn++) {
        int cc = n0 + wn + fn * 16 + col;
        P[((size_t)b * NP + row) * NN + cc] = f2b(acc[fm][fn][rg] + bias);
      }
    }
}

// ---------------------------------------------------------------------------
// K2: softmax over p (1024) per (b,n) column, in-place on P, plus per-block
// rowsum partials (deterministic; no atomics).
// grid (NN/64, NB), 256 thr: cg=tid&7 -> 8 cols (ushort8), pg=tid>>3 -> 32 rows
// ---------------------------------------------------------------------------
__global__ __launch_bounds__(256) void k2_softmax(ushort_t* __restrict__ P,
                                                  float* __restrict__ sPpart) {
  __shared__ float lm[32][64];
  __shared__ float ls[32][64];
  __shared__ float Mf[64], If[64];
  const int tid = threadIdx.x;
  const int n0 = blockIdx.x * 64, b = blockIdx.y;
  const int cg = tid & 7, pg = tid >> 3;
  ushort_t* base = P + (size_t)b * NP * NN + n0 + cg * 8;

  float m[8], s[8];
#pragma unroll
  for (int j = 0; j < 8; j++) { m[j] = -3.0e38f; s[j] = 0.f; }
  for (int r = 0; r < 32; r++) {
    int p = pg * 32 + r;
    ushort8_t v = *(const ushort8_t*)(base + (size_t)p * NN);
#pragma unroll
    for (int j = 0; j < 8; j++) {
      float x = b2f(v[j]);
      float mn = fmaxf(m[j], x);
      s[j] = s[j] * __expf(m[j] - mn) + __expf(x - mn);
      m[j] = mn;
    }
  }
#pragma unroll
  for (int j = 0; j < 8; j++) { lm[pg][cg * 8 + j] = m[j]; ls[pg][cg * 8 + j] = s[j]; }
  __syncthreads();
  if (tid < 64) {
    float M = -3.0e38f, S = 0.f;
    for (int g = 0; g < 32; g++) {
      float mg = lm[g][tid], sg = ls[g][tid];
      float Mn = fmaxf(M, mg);
      S = S * __expf(M - Mn) + sg * __expf(mg - Mn);
      M = Mn;
    }
    Mf[tid] = M;
    If[tid] = 1.f / S;
  }
  __syncthreads();
  float mj[8], ij[8];
#pragma unroll
  for (int j = 0; j < 8; j++) { mj[j] = Mf[cg * 8 + j]; ij[j] = If[cg * 8 + j]; }
  for (int r = 0; r < 32; r++) {
    int p = pg * 32 + r;
    ushort_t* rp = base + (size_t)p * NN;
    ushort8_t v = *(const ushort8_t*)rp;
    ushort8_t o;
    float rs = 0.f;
#pragma unroll
    for (int j = 0; j < 8; j++) {
      float e = __expf(b2f(v[j]) - mj[j]) * ij[j];
      o[j] = f2b(e);
      rs += e;
    }
    *(ushort8_t*)rp = o;
    rs += __shfl_xor(rs, 1, 64);
    rs += __shfl_xor(rs, 2, 64);
    rs += __shfl_xor(rs, 4, 64);
    if (cg == 0) sPpart[((size_t)blockIdx.x * NB + b) * NP + p] = rs;
  }
}

// K2r: sP[b,p] = sum over 64 n-blocks of sPpart
__global__ __launch_bounds__(256) void k2r_reduce(const float* __restrict__ sPpart,
                                                  float* __restrict__ sP) {
  int idx = blockIdx.x * 256 + threadIdx.x;  // b*NP + p
  float s = 0.f;
#pragma unroll 8
  for (int bx = 0; bx < 64; bx++) s += sPpart[(size_t)bx * (NB * NP) + idx];
  sP[idx] = s;
}

// ---------------------------------------------------------------------------
// K3: XR4[ks][b][c][p] = sum_{n in slice ks} xb[b,c,n] * P[b,p,n]
// 128x128 tile, BK=32, glds both operands, split-K=2.
// ---------------------------------------------------------------------------
__global__ __launch_bounds__(256) void k3_pool(const ushort_t* __restrict__ xb,
                                               const ushort_t* __restrict__ P,
                                               float* __restrict__ XR4) {
  __shared__ __align__(16) ushort_t As[128 * 32];
  __shared__ __align__(16) ushort_t Bs[128 * 32];
  const int tid = threadIdx.x;
  const int n0 = blockIdx.x * 128, m0 = blockIdx.y * 128;
  const int b = blockIdx.z >> 1, ks = blockIdx.z & 1;
  const int lane = tid & 63, w = tid >> 6;
  const int wm = (w >> 1) * 64, wn = (w & 1) * 64;
  const int srow = tid >> 2, koff = (tid & 3) * 8;
  ushort_t* A0 = As + w * 512;
  ushort_t* A1 = As + 2048 + w * 512;
  ushort_t* B0 = Bs + w * 512;
  ushort_t* B1 = Bs + 2048 + w * 512;
  const ushort_t* Asrc = xb + ((size_t)b * NC + m0 + srow) * NN + koff;
  const ushort_t* Bsrc = P + ((size_t)b * NP + n0 + srow) * NN + koff;
  f32x4 acc[4][4] = {};
  const int fr = lane & 15, kq = (lane >> 4) * 8;
  const int kbeg = ks * 2048, kend = kbeg + 2048;
  for (int k0 = kbeg; k0 < kend; k0 += 32) {
    glds16(Asrc + k0, A0);
    glds16(Asrc + (size_t)64 * NN + k0, A1);
    glds16(Bsrc + k0, B0);
    glds16(Bsrc + (size_t)64 * NN + k0, B1);
    __syncthreads();
    bf16x8 af[4], bf[4];
#pragma unroll
    for (int f = 0; f < 4; f++) {
      af[f] = *(const bf16x8*)&As[(wm + f * 16 + fr) * 32 + kq];
      bf[f] = *(const bf16x8*)&Bs[(wn + f * 16 + fr) * 32 + kq];
    }
#pragma unroll
    for (int fm = 0; fm < 4; fm++)
#pragma unroll
      for (int fn = 0; fn < 4; fn++) acc[fm][fn] = mfma16(af[fm], bf[fn], acc[fm][fn]);
    __syncthreads();
  }
  const int col = lane & 15, rb = (lane >> 4) * 4;
  float* outp = XR4 + (size_t)(ks * NB + b) * NC * NP;
#pragma unroll
  for (int fm = 0; fm < 4; fm++)
#pragma unroll
    for (int fn = 0; fn < 4; fn++)
#pragma unroll
      for (int rg = 0; rg < 4; rg++) {
        int row = m0 + wm + fm * 16 + rb + rg;  // c
        int cc = n0 + wn + fn * 16 + col;       // p
        outp[(size_t)row * NP + cc] = acc[fm][fn][rg];
      }
}

// ---------------------------------------------------------------------------
// K4: per-(b,h) tiny attention -> Tmb (bf16)
// ---------------------------------------------------------------------------
__global__ __launch_bounds__(256) void k4_attn(const float* __restrict__ XR4,
                                               const float* __restrict__ sP,
                                               const float* __restrict__ Wqkv,
                                               const float* __restrict__ bqkv,
                                               const float* __restrict__ Wout,
                                               ushort_t* __restrict__ Tmb) {
  const int bh = blockIdx.x;
  const int b = bh >> 3, h = bh & 7;
  const int tid = threadIdx.x;
  __shared__ float Ws[96][64];
  __shared__ float XRs[64][128];
  __shared__ float qf[96][64];
  __shared__ float attn_sT[64][65];
  __shared__ float vals_s[32][64];
  __shared__ float sPq_s[64], sPk_s[64];

  if (tid < 64) sPq_s[tid] = sP[(size_t)b * NP + h * 128 + tid];
  else if (tid < 128) sPk_s[tid - 64] = sP[(size_t)b * NP + h * 128 + tid];

  float acc1[24];
#pragma unroll
  for (int r = 0; r < 24; r++) acc1[r] = 0.f;

  const size_t slice = (size_t)NB * NC * NP;
  for (int c0 = 0; c0 < NC; c0 += 64) {
    __syncthreads();
    for (int u = tid; u < 96 * 64; u += 256) {
      int rw = u >> 6, cc = u & 63;
      Ws[rw][cc] = Wqkv[(size_t)(h * 96 + rw) * NC + c0 + cc];
    }
    for (int u = tid; u < 64 * 128; u += 256) {
      int rw = u >> 7, cc = u & 127;
      size_t bi = ((size_t)b * NC + c0 + rw) * NP + h * 128 + cc;
      XRs[rw][cc] = XR4[bi] + XR4[bi + slice];
    }
    __syncthreads();
#pragma unroll
    for (int r = 0; r < 24; r++) {
      int idx = r * 256 + tid;
      int row = idx >> 6, j = idx & 63;
      int cb = (row < 32) ? 0 : 64;
      float a = 0.f;
#pragma unroll 8
      for (int cc = 0; cc < 64; cc++) a += Ws[row][cc] * XRs[cc][cb + j];
      acc1[r] += a;
    }
  }
  __syncthreads();
#pragma unroll
  for (int r = 0; r < 24; r++) {
    int idx = r * 256 + tid;
    int row = idx >> 6, j = idx & 63;
    float bias = bqkv[h * 96 + row] * ((row < 32) ? sPq_s[j] : sPk_s[j]);
    qf[row][j] = acc1[r] + bias;
  }
  __syncthreads();
  const float isc = 0.17677669529663687f;
#pragma unroll
  for (int r = 0; r < 16; r++) {
    int o = r * 256 + tid;
    int qi = o >> 6, ki = o & 63;
    float a = 0.f;
#pragma unroll 8
    for (int dd = 0; dd < 32; dd++) a += qf[dd][qi] * qf[32 + dd][ki];
    attn_sT[ki][qi] = a * isc;
  }
  __syncthreads();
  if (tid < 64) {
    float m = -3e38f;
    for (int k = 0; k < 64; k++) m = fmaxf(m, attn_sT[k][tid]);
    float s = 0.f;
    for (int k = 0; k < 64; k++) {
      float e = __expf(attn_sT[k][tid] - m);
      attn_sT[k][tid] = e;
      s += e;
    }
    float inv = 1.f / s;
    for (int k = 0; k < 64; k++) attn_sT[k][tid] *= inv;
  }
  __syncthreads();
#pragma unroll
  for (int r = 0; r < 8; r++) {
    int o = r * 256 + tid;
    int dd = o >> 6, q = o & 63;
    float a = 0.f;
#pragma unroll 8
    for (int k = 0; k < 64; k++) a += qf[64 + dd][k] * attn_sT[k][q];
    vals_s[dd][q] = a;
  }
  __syncthreads();
  for (int r = 0; r < 64; r++) {
    int o = r * 256 + tid;
    int c = o >> 6, j = o & 63;
    float a = 0.f;
#pragma unroll 8
    for (int dd = 0; dd < 32; dd++)
      a += Wout[(size_t)c * NC + h * 32 + dd] * vals_s[dd][j];
    Tmb[((size_t)b * NC + c) * NT + h * 64 + j] = f2b(a);
  }
}

// ---------------------------------------------------------------------------
// K5: out = x + alpha*(Tmb·Pq + bout). 128x128 tile; A glds, B transpose-stage.
// ---------------------------------------------------------------------------
__global__ __launch_bounds__(256) void k5_out(const float* __restrict__ x,
                                              const ushort_t* __restrict__ P,
                                              const ushort_t* __restrict__ Tmb,
                                              const float* __restrict__ bout,
                                              const float* __restrict__ alpha,
                                              float* __restrict__ out) {
  __shared__ __align__(16) ushort_t As[128 * 32];
  __shared__ __align__(16) ushort_t Bs[128 * 40];
  const int tid = threadIdx.x;
  const int n0 = blockIdx.x * 128, m0 = blockIdx.y * 128, b = blockIdx.z;
  const int lane = tid & 63, w = tid >> 6;
  const int wm = (w >> 1) * 64, wn = (w & 1) * 64;
  const int srow = tid >> 2, koff = (tid & 3) * 8;
  ushort_t* A0 = As + w * 512;
  ushort_t* A1 = As + 2048 + w * 512;
  const ushort_t* Asrc = Tmb + ((size_t)b * NC + m0 + srow) * NT + koff;
  const int kg = tid >> 5, ng = (tid & 31) * 4;
  f32x4 acc[4][4] = {};
  const int fr = lane & 15, kq = (lane >> 4) * 8;
  for (int k0 = 0; k0 < NT; k0 += 32) {
    glds16(Asrc + k0, A0);
    glds16(Asrc + (size_t)64 * NT + k0, A1);
#pragma unroll
    for (int i = 0; i < 4; i++) {
      int hj = k0 + kg * 4 + i;
      int prow = ((hj >> 6) << 7) + (hj & 63);
      ushort4_t v = *(const ushort4_t*)(P + ((size_t)b * NP + prow) * NN + n0 + ng);
#pragma unroll
      for (int jj = 0; jj < 4; jj++) Bs[(ng + jj) * 40 + kg * 4 + i] = v[jj];
    }
    __syncthreads();
    bf16x8 af[4], bf[4];
#pragma unroll
    for (int f = 0; f < 4; f++) {
      af[f] = *(const bf16x8*)&As[(wm + f * 16 + fr) * 32 + kq];
      bf[f] = *(const bf16x8*)&Bs[(wn + f * 16 + fr) * 40 + kq];
    }
#pragma unroll
    for (int fm = 0; fm < 4; fm++)
#pragma unroll
      for (int fn = 0; fn < 4; fn++) acc[fm][fn] = mfma16(af[fm], bf[fn], acc[fm][fn]);
    __syncthreads();
  }
  const float al = alpha[0];
  const int col = lane & 15, rb = (lane >> 4) * 4;
#pragma unroll
  for (int fm = 0; fm < 4; fm++)
#pragma unroll
    for (int rg = 0; rg < 4; rg++) {
      int row = m0 + wm + fm * 16 + rb + rg;
      float bias = bout[row];
#pragma unroll
      for (int fn = 0; fn < 4; fn++) {
        int cc = n0 + wn + fn * 16 + col;
        size_t idx = ((size_t)b * NC + row) * NN + cc;
        out[idx] = x[idx] + al * (acc[fm][fn][rg] + bias);
      }
    }
}

// ---------------------------------------------------------------------------
extern "C" void kernel_launch(void* const* d_in, const int* in_sizes, int n_in,
                              void* d_out, int out_size, void* d_ws, size_t ws_size,
                              hipStream_t stream) {
  const float* x = (const float*)d_in[0];
  const float* Wqkv = (const float*)d_in[1];
  const float* bqkv = (const float*)d_in[2];
  const float* Wr = (const float*)d_in[3];
  const float* br = (const float*)d_in[4];
  const float* Wout = (const float*)d_in[5];
  const float* bout = (const float*)d_in[6];
  const float* alpha = (const float*)d_in[7];
  float* out = (float*)d_out;

  char* ws = (char*)d_ws;
  ushort_t* P = (ushort_t*)ws;                        // 134,217,728 B
  ushort_t* xb = (ushort_t*)(ws + 134217728);         // 33,554,432 B
  ushort_t* xt = (ushort_t*)(ws + 167772160);         // 33,554,432 B (dead after k1)
  float* XR4 = (float*)(ws + 167772160);              // aliases xt: 33,554,432 B
  ushort_t* Wrb = (ushort_t*)(ws + 201326592);        // 524,288 B
  float* sPpart = (float*)(ws + 201850880);           // 4,194,304 B
  float* sP = (float*)(ws + 206045184);               // 65,536 B
  ushort_t* Tmb = (ushort_t*)(ws + 206110720);        // 4,194,304 B -> end 210,305,024

  k0_cvt<<<dim3(64, 4, 16), 256, 0, stream>>>(x, xb, xt);
  k0b_wr<<<dim3(256), 256, 0, stream>>>(Wr, Wrb);
  k1_proj<<<dim3(32, 8, 16), 256, 0, stream>>>(Wrb, xt, br, P);
  k2_softmax<<<dim3(64, 16), 256, 0, stream>>>(P, sPpart);
  k2r_reduce<<<dim3(64), 256, 0, stream>>>(sPpart, sP);
  k3_pool<<<dim3(8, 2, 32), 256, 0, stream>>>(xb, P, XR4);
  k4_attn<<<dim3(128), 256, 0, stream>>>(XR4, sP, Wqkv, bqkv, Wout, Tmb);
  k5_out<<<dim3(32, 2, 16), 256, 0, stream>>>(x, P, Tmb, bout, alpha, out);
}

// Round 3
// 334.722 us; speedup vs baseline: 2.2209x; 1.2945x over previous
//
#include <hip/hip_runtime.h>
#include <cstdint>

typedef unsigned short ushort_t;
typedef __attribute__((ext_vector_type(4))) unsigned short ushort4_t;
typedef __attribute__((ext_vector_type(8))) unsigned short ushort8_t;
typedef __attribute__((ext_vector_type(8))) __bf16 bf16x8;
typedef __attribute__((ext_vector_type(4))) float f32x4;

constexpr int NB = 16;    // batch
constexpr int NC = 256;   // channels C (== E)
constexpr int NN = 4096;  // tokens N = H*W
constexpr int NP = 1024;  // region-proj channels = 2*R*heads
constexpr int NT = 512;   // heads * R (Rq columns of T)
constexpr int NO = 768;   // 3*E rows of Wqkv

static __device__ __forceinline__ ushort_t f2b(float f) {
  uint32_t u = __builtin_bit_cast(uint32_t, f);
  u += 0x7FFFu + ((u >> 16) & 1u);
  return (ushort_t)(u >> 16);
}
static __device__ __forceinline__ float b2f(ushort_t h) {
  return __builtin_bit_cast(float, (uint32_t)h << 16);
}
static __device__ __forceinline__ f32x4 mfma16(bf16x8 a, bf16x8 b, f32x4 c) {
  return __builtin_amdgcn_mfma_f32_16x16x32_bf16(a, b, c, 0, 0, 0);
}
typedef __attribute__((address_space(1))) const unsigned int guint;
typedef __attribute__((address_space(3))) unsigned int luint;
static __device__ __forceinline__ void glds16(const void* g, void* l) {
  __builtin_amdgcn_global_load_lds((guint*)g, (luint*)l, 16, 0, 0);
}

// ---------------------------------------------------------------------------
// K0: x (f32 [b][c][n]) -> xb (bf16 [b][c][n]) and xt (bf16 [b][n][c])
// ---------------------------------------------------------------------------
__global__ __launch_bounds__(256) void k0_cvt(const float* __restrict__ x,
                                              ushort_t* __restrict__ xb,
                                              ushort_t* __restrict__ xt) {
  __shared__ ushort_t tr[64][88];
  const int tid = threadIdx.x;
  const int n0 = blockIdx.x * 64, c0 = blockIdx.y * 64, b = blockIdx.z;
  const int cr = (tid >> 4) * 4;
  const int nc4 = (tid & 15) * 4;
#pragma unroll
  for (int i = 0; i < 4; i++) {
    size_t idx = ((size_t)b * NC + c0 + cr + i) * NN + n0 + nc4;
    float4 v = *(const float4*)(x + idx);
    ushort4_t o;
    o[0] = f2b(v.x); o[1] = f2b(v.y); o[2] = f2b(v.z); o[3] = f2b(v.w);
    *(ushort4_t*)(xb + idx) = o;
    tr[nc4 + 0][cr + i] = o[0];
    tr[nc4 + 1][cr + i] = o[1];
    tr[nc4 + 2][cr + i] = o[2];
    tr[nc4 + 3][cr + i] = o[3];
  }
  __syncthreads();
  const int nr = tid >> 2, cc0 = (tid & 3) * 16;
  size_t odx = ((size_t)b * NN + n0 + nr) * NC + c0 + cc0;
  *(ushort8_t*)(xt + odx) = *(const ushort8_t*)&tr[nr][cc0];
  *(ushort8_t*)(xt + odx + 8) = *(const ushort8_t*)&tr[nr][cc0 + 8];
}

// generic f32 -> bf16 (count multiple of 1024)
__global__ __launch_bounds__(256) void cvt_f2b_k(const float* __restrict__ src,
                                                 ushort_t* __restrict__ dst) {
  int i = (blockIdx.x * 256 + threadIdx.x) * 4;
  float4 v = *(const float4*)(src + i);
  ushort4_t o;
  o[0] = f2b(v.x); o[1] = f2b(v.y); o[2] = f2b(v.z); o[3] = f2b(v.w);
  *(ushort4_t*)(dst + i) = o;
}

// ---------------------------------------------------------------------------
// K1: P[b,p,n] = Wrb[p,:]·xt[b,n,:] + br[p]   (bf16 out, pre-softmax)
// 128x128, BK=32, glds both. 1D grid 4096, XCD swizzle, m fastest (B reuse).
// ---------------------------------------------------------------------------
__global__ __launch_bounds__(256) void k1_proj(const ushort_t* __restrict__ Wrb,
                                               const ushort_t* __restrict__ xt,
                                               const float* __restrict__ br,
                                               ushort_t* __restrict__ P) {
  __shared__ __align__(16) ushort_t As[128 * 32];
  __shared__ __align__(16) ushort_t Bs[128 * 32];
  const int tid = threadIdx.x;
  const int ord = blockIdx.x;
  const int L = (ord & 7) * 512 + (ord >> 3);
  const int m0 = (L & 7) * 128;
  const int n0 = ((L >> 3) & 31) * 128;
  const int b = L >> 8;
  const int lane = tid & 63, w = tid >> 6;
  const int wm = (w >> 1) * 64, wn = (w & 1) * 64;
  const int srow = tid >> 2, koff = (tid & 3) * 8;
  ushort_t* A0 = As + w * 512;
  ushort_t* A1 = As + 2048 + w * 512;
  ushort_t* B0 = Bs + w * 512;
  ushort_t* B1 = Bs + 2048 + w * 512;
  const ushort_t* Asrc = Wrb + (size_t)(m0 + srow) * NC + koff;
  const ushort_t* Bsrc = xt + ((size_t)b * NN + n0 + srow) * NC + koff;
  f32x4 acc[4][4] = {};
  const int fr = lane & 15, kq = (lane >> 4) * 8;
  for (int k0 = 0; k0 < NC; k0 += 32) {
    glds16(Asrc + k0, A0);
    glds16(Asrc + (size_t)64 * NC + k0, A1);
    glds16(Bsrc + k0, B0);
    glds16(Bsrc + (size_t)64 * NC + k0, B1);
    __syncthreads();
    bf16x8 af[4], bf[4];
#pragma unroll
    for (int f = 0; f < 4; f++) {
      af[f] = *(const bf16x8*)&As[(wm + f * 16 + fr) * 32 + kq];
      bf[f] = *(const bf16x8*)&Bs[(wn + f * 16 + fr) * 32 + kq];
    }
#pragma unroll
    for (int fm = 0; fm < 4; fm++)
#pragma unroll
      for (int fn = 0; fn < 4; fn++) acc[fm][fn] = mfma16(af[fm], bf[fn], acc[fm][fn]);
    __syncthreads();
  }
  const int col = lane & 15, rb = (lane >> 4) * 4;
#pragma unroll
  for (int fm = 0; fm < 4; fm++)
#pragma unroll
    for (int rg = 0; rg < 4; rg++) {
      int row = m0 + wm + fm * 16 + rb + rg;
      float bias = br[row];
#pragma unroll
      for (int fn = 0; fn < 4; fn++) {
        int cc = n0 + wn + fn * 16 + col;
        P[((size_t)b * NP + row) * NN + cc] = f2b(acc[fm][fn][rg] + bias);
      }
    }
}

// ---------------------------------------------------------------------------
// K2: softmax over p (1024) per (b,n) column, in-place. 512 threads, rows in
// registers (single global read). Also emits per-block rowsum partials.
// ---------------------------------------------------------------------------
__global__ __launch_bounds__(512) void k2_softmax(ushort_t* __restrict__ P,
                                                  float* __restrict__ sPpart) {
  __shared__ float red[64][64];
  __shared__ float Mf[64], If[64];
  const int tid = threadIdx.x;
  const int n0 = blockIdx.x * 64, b = blockIdx.y;
  const int cg = tid & 7, pg = tid >> 3;  // pg in [0,64), 16 rows each
  ushort_t* base = P + (size_t)b * NP * NN + n0 + cg * 8;

  ushort8_t v[16];
  float m[8];
#pragma unroll
  for (int j = 0; j < 8; j++) m[j] = -3.0e38f;
#pragma unroll
  for (int r = 0; r < 16; r++) {
    v[r] = *(const ushort8_t*)(base + (size_t)(pg * 16 + r) * NN);
#pragma unroll
    for (int j = 0; j < 8; j++) m[j] = fmaxf(m[j], b2f(v[r][j]));
  }
#pragma unroll
  for (int j = 0; j < 8; j++) red[pg][cg * 8 + j] = m[j];
  __syncthreads();
  if (tid < 64) {
    float M = -3.0e38f;
    for (int g = 0; g < 64; g++) M = fmaxf(M, red[g][tid]);
    Mf[tid] = M;
  }
  __syncthreads();
  float mj[8], s[8];
#pragma unroll
  for (int j = 0; j < 8; j++) { mj[j] = Mf[cg * 8 + j]; s[j] = 0.f; }
#pragma unroll
  for (int r = 0; r < 16; r++)
#pragma unroll
    for (int j = 0; j < 8; j++) s[j] += __expf(b2f(v[r][j]) - mj[j]);
#pragma unroll
  for (int j = 0; j < 8; j++) red[pg][cg * 8 + j] = s[j];
  __syncthreads();
  if (tid < 64) {
    float S = 0.f;
    for (int g = 0; g < 64; g++) S += red[g][tid];
    If[tid] = 1.f / S;
  }
  __syncthreads();
  float ij[8];
#pragma unroll
  for (int j = 0; j < 8; j++) ij[j] = If[cg * 8 + j];
#pragma unroll
  for (int r = 0; r < 16; r++) {
    int p = pg * 16 + r;
    ushort8_t o;
    float rs = 0.f;
#pragma unroll
    for (int j = 0; j < 8; j++) {
      float e = __expf(b2f(v[r][j]) - mj[j]) * ij[j];
      o[j] = f2b(e);
      rs += e;
    }
    *(ushort8_t*)(base + (size_t)p * NN) = o;
    rs += __shfl_xor(rs, 1, 64);
    rs += __shfl_xor(rs, 2, 64);
    rs += __shfl_xor(rs, 4, 64);
    if (cg == 0) sPpart[((size_t)blockIdx.x * NB + b) * NP + p] = rs;
  }
}

// K2r: sP[b,p] = sum over 64 n-blocks
__global__ __launch_bounds__(256) void k2r_reduce(const float* __restrict__ sPpart,
                                                  float* __restrict__ sP) {
  int idx = blockIdx.x * 256 + threadIdx.x;
  float s = 0.f;
#pragma unroll 8
  for (int bx = 0; bx < 64; bx++) s += sPpart[(size_t)bx * (NB * NP) + idx];
  sP[idx] = s;
}

// ---------------------------------------------------------------------------
// K3: XR4[ks][b][c][p] = sum_{n in slice ks} xb[b,c,n]·P[b,p,n]. split-K=2.
// 1D grid 512, XCD swizzle, c fastest (P-tile reuse).
// ---------------------------------------------------------------------------
__global__ __launch_bounds__(256) void k3_pool(const ushort_t* __restrict__ xb,
                                               const ushort_t* __restrict__ P,
                                               float* __restrict__ XR4) {
  __shared__ __align__(16) ushort_t As[128 * 32];
  __shared__ __align__(16) ushort_t Bs[128 * 32];
  const int tid = threadIdx.x;
  const int ord = blockIdx.x;
  const int L = (ord & 7) * 64 + (ord >> 3);
  const int m0 = (L & 1) * 128;          // c
  const int n0 = ((L >> 1) & 7) * 128;   // p
  const int zz = L >> 4;
  const int b = zz >> 1, ks = zz & 1;
  const int lane = tid & 63, w = tid >> 6;
  const int wm = (w >> 1) * 64, wn = (w & 1) * 64;
  const int srow = tid >> 2, koff = (tid & 3) * 8;
  ushort_t* A0 = As + w * 512;
  ushort_t* A1 = As + 2048 + w * 512;
  ushort_t* B0 = Bs + w * 512;
  ushort_t* B1 = Bs + 2048 + w * 512;
  const ushort_t* Asrc = xb + ((size_t)b * NC + m0 + srow) * NN + koff;
  const ushort_t* Bsrc = P + ((size_t)b * NP + n0 + srow) * NN + koff;
  f32x4 acc[4][4] = {};
  const int fr = lane & 15, kq = (lane >> 4) * 8;
  const int kbeg = ks * 2048, kend = kbeg + 2048;
  for (int k0 = kbeg; k0 < kend; k0 += 32) {
    glds16(Asrc + k0, A0);
    glds16(Asrc + (size_t)64 * NN + k0, A1);
    glds16(Bsrc + k0, B0);
    glds16(Bsrc + (size_t)64 * NN + k0, B1);
    __syncthreads();
    bf16x8 af[4], bf[4];
#pragma unroll
    for (int f = 0; f < 4; f++) {
      af[f] = *(const bf16x8*)&As[(wm + f * 16 + fr) * 32 + kq];
      bf[f] = *(const bf16x8*)&Bs[(wn + f * 16 + fr) * 32 + kq];
    }
#pragma unroll
    for (int fm = 0; fm < 4; fm++)
#pragma unroll
      for (int fn = 0; fn < 4; fn++) acc[fm][fn] = mfma16(af[fm], bf[fn], acc[fm][fn]);
    __syncthreads();
  }
  const int col = lane & 15, rb = (lane >> 4) * 4;
  float* outp = XR4 + (size_t)(ks * NB + b) * NC * NP;
#pragma unroll
  for (int fm = 0; fm < 4; fm++)
#pragma unroll
    for (int fn = 0; fn < 4; fn++)
#pragma unroll
      for (int rg = 0; rg < 4; rg++) {
        int row = m0 + wm + fm * 16 + rb + rg;
        int cc = n0 + wn + fn * 16 + col;
        outp[(size_t)row * NP + cc] = acc[fm][fn][rg];
      }
}

// ---------------------------------------------------------------------------
// K3r: XRbT[b][p][c] = f2b(XR4[0][b][c][p] + XR4[1][b][c][p])  (transpose)
// ---------------------------------------------------------------------------
__global__ __launch_bounds__(256) void k3r_tr(const float* __restrict__ XR4,
                                              ushort_t* __restrict__ XRbT) {
  __shared__ ushort_t tr[64][72];
  const int tid = threadIdx.x;
  const int p0 = blockIdx.x * 64, c0 = blockIdx.y * 64, b = blockIdx.z;
  const size_t slice = (size_t)NB * NC * NP;
  const int row = tid >> 4, col4 = (tid & 15) * 4;
#pragma unroll
  for (int i = 0; i < 4; i++) {
    int c = row + i * 16;
    size_t idx = ((size_t)b * NC + c0 + c) * NP + p0 + col4;
    float4 v0 = *(const float4*)(XR4 + idx);
    float4 v1 = *(const float4*)(XR4 + idx + slice);
    tr[col4 + 0][c] = f2b(v0.x + v1.x);
    tr[col4 + 1][c] = f2b(v0.y + v1.y);
    tr[col4 + 2][c] = f2b(v0.z + v1.z);
    tr[col4 + 3][c] = f2b(v0.w + v1.w);
  }
  __syncthreads();
  const int prow = tid >> 2, coff = (tid & 3) * 16;
  size_t odx = ((size_t)b * NP + p0 + prow) * NC + c0 + coff;
  *(ushort8_t*)(XRbT + odx) = *(const ushort8_t*)&tr[prow][coff];
  *(ushort8_t*)(XRbT + odx + 8) = *(const ushort8_t*)&tr[prow][coff + 8];
}

// ---------------------------------------------------------------------------
// K4a: QKVRb[b][o][p] = f2b( Wqkvb[o,:]·XRbT[b,p,:] + bqkv[o]·sP[b,p] )
// M=768 N=1024 K=256. 1D grid 768, XCD swizzle, o fastest.
// ---------------------------------------------------------------------------
__global__ __launch_bounds__(256) void k4a_qkvr(const ushort_t* __restrict__ Wqkvb,
                                                const ushort_t* __restrict__ XRbT,
                                                const float* __restrict__ bqkv,
                                                const float* __restrict__ sP,
                                                ushort_t* __restrict__ QKVRb) {
  __shared__ __align__(16) ushort_t As[128 * 32];
  __shared__ __align__(16) ushort_t Bs[128 * 32];
  const int tid = threadIdx.x;
  const int ord = blockIdx.x;
  const int L = (ord & 7) * 96 + (ord >> 3);
  const int m0 = (L % 6) * 128;
  const int rest = L / 6;
  const int n0 = (rest & 7) * 128;
  const int b = rest >> 3;
  const int lane = tid & 63, w = tid >> 6;
  const int wm = (w >> 1) * 64, wn = (w & 1) * 64;
  const int srow = tid >> 2, koff = (tid & 3) * 8;
  ushort_t* A0 = As + w * 512;
  ushort_t* A1 = As + 2048 + w * 512;
  ushort_t* B0 = Bs + w * 512;
  ushort_t* B1 = Bs + 2048 + w * 512;
  const ushort_t* Asrc = Wqkvb + (size_t)(m0 + srow) * NC + koff;
  const ushort_t* Bsrc = XRbT + ((size_t)b * NP + n0 + srow) * NC + koff;
  f32x4 acc[4][4] = {};
  const int fr = lane & 15, kq = (lane >> 4) * 8;
  for (int k0 = 0; k0 < NC; k0 += 32) {
    glds16(Asrc + k0, A0);
    glds16(Asrc + (size_t)64 * NC + k0, A1);
    glds16(Bsrc + k0, B0);
    glds16(Bsrc + (size_t)64 * NC + k0, B1);
    __syncthreads();
    bf16x8 af[4], bf[4];
#pragma unroll
    for (int f = 0; f < 4; f++) {
      af[f] = *(const bf16x8*)&As[(wm + f * 16 + fr) * 32 + kq];
      bf[f] = *(const bf16x8*)&Bs[(wn + f * 16 + fr) * 32 + kq];
    }
#pragma unroll
    for (int fm = 0; fm < 4; fm++)
#pragma unroll
      for (int fn = 0; fn < 4; fn++) acc[fm][fn] = mfma16(af[fm], bf[fn], acc[fm][fn]);
    __syncthreads();
  }
  const int col = lane & 15, rb = (lane >> 4) * 4;
  float spv[4];
#pragma unroll
  for (int fn = 0; fn < 4; fn++) spv[fn] = sP[(size_t)b * NP + n0 + wn + fn * 16 + col];
#pragma unroll
  for (int fm = 0; fm < 4; fm++)
#pragma unroll
    for (int rg = 0; rg < 4; rg++) {
      int row = m0 + wm + fm * 16 + rb + rg;
      float bq = bqkv[row];
#pragma unroll
      for (int fn = 0; fn < 4; fn++) {
        int cc = n0 + wn + fn * 16 + col;
        QKVRb[((size_t)b * NO + row) * NP + cc] = f2b(acc[fm][fn][rg] + bq * spv[fn]);
      }
    }
}

// ---------------------------------------------------------------------------
// K4b: per-(b,h) tiny attention + Wout fold -> Tmb (bf16)
// ---------------------------------------------------------------------------
__global__ __launch_bounds__(256) void k4b_attn(const ushort_t* __restrict__ QKVRb,
                                                const float* __restrict__ Wout,
                                                ushort_t* __restrict__ Tmb) {
  const int b = blockIdx.x >> 3, h = blockIdx.x & 7;
  const int tid = threadIdx.x;
  __shared__ float qf[96][64];       // q(0:32) k(32:64) v(64:96)
  __shared__ float attn_sT[64][65];  // [k][q]
  __shared__ float vals_s[32][64];
#pragma unroll
  for (int i = 0; i < 3; i++) {
    int u = i * 256 + tid;
    int rw = u >> 3, jc = (u & 7) * 8;
    int p0 = h * 128 + ((rw < 32) ? 0 : 64);
    ushort8_t v = *(const ushort8_t*)(QKVRb + ((size_t)b * NO + h * 96 + rw) * NP + p0 + jc);
#pragma unroll
    for (int j = 0; j < 8; j++) qf[rw][jc + j] = b2f(v[j]);
  }
  __syncthreads();
  const int lj = tid & 63;  // fixed column for this thread
  const int rq = tid >> 6;  // 0..3
  float kcol[32];
#pragma unroll
  for (int dd = 0; dd < 32; dd++) kcol[dd] = qf[32 + dd][lj];
  const float isc = 0.17677669529663687f;
#pragma unroll
  for (int r = 0; r < 16; r++) {
    int qi = r * 4 + rq;
    float a = 0.f;
#pragma unroll
    for (int dd = 0; dd < 32; dd++) a += qf[dd][qi] * kcol[dd];
    attn_sT[lj][qi] = a * isc;
  }
  __syncthreads();
  if (tid < 64) {
    float m = -3e38f;
    for (int k = 0; k < 64; k++) m = fmaxf(m, attn_sT[k][tid]);
    float s = 0.f;
    for (int k = 0; k < 64; k++) {
      float e = __expf(attn_sT[k][tid] - m);
      attn_sT[k][tid] = e;
      s += e;
    }
    float inv = 1.f / s;
    for (int k = 0; k < 64; k++) attn_sT[k][tid] *= inv;
  }
  __syncthreads();
  float acol[64];
#pragma unroll
  for (int k = 0; k < 64; k++) acol[k] = attn_sT[k][lj];
#pragma unroll
  for (int r = 0; r < 8; r++) {
    int dd = r * 4 + rq;
    float a = 0.f;
#pragma unroll
    for (int k = 0; k < 64; k++) a += qf[64 + dd][k] * acol[k];
    vals_s[dd][lj] = a;
  }
  __syncthreads();
  float vcol[32];
#pragma unroll
  for (int dd = 0; dd < 32; dd++) vcol[dd] = vals_s[dd][lj];
  for (int r = 0; r < 64; r++) {
    int c = r * 4 + rq;
    const float4* wp = (const float4*)(Wout + (size_t)c * NC + h * 32);
    float a = 0.f;
#pragma unroll
    for (int t = 0; t < 8; t++) {
      float4 w = wp[t];
      a += w.x * vcol[t * 4] + w.y * vcol[t * 4 + 1] + w.z * vcol[t * 4 + 2] +
           w.w * vcol[t * 4 + 3];
    }
    Tmb[((size_t)b * NC + c) * NT + h * 64 + lj] = f2b(a);
  }
}

// ---------------------------------------------------------------------------
// K5: out = x + alpha*(Tmb·Pq + bout). 1D grid 1024, swizzle, c fastest.
// ---------------------------------------------------------------------------
__global__ __launch_bounds__(256) void k5_out(const float* __restrict__ x,
                                              const ushort_t* __restrict__ P,
                                              const ushort_t* __restrict__ Tmb,
                                              const float* __restrict__ bout,
                                              const float* __restrict__ alpha,
                                              float* __restrict__ out) {
  __shared__ __align__(16) ushort_t As[128 * 32];
  __shared__ __align__(16) ushort_t Bs[128 * 40];
  const int tid = threadIdx.x;
  const int ord = blockIdx.x;
  const int L = (ord & 7) * 128 + (ord >> 3);
  const int m0 = (L & 1) * 128;
  const int n0 = ((L >> 1) & 31) * 128;
  const int b = L >> 6;
  const int lane = tid & 63, w = tid >> 6;
  const int wm = (w >> 1) * 64, wn = (w & 1) * 64;
  const int srow = tid >> 2, koff = (tid & 3) * 8;
  ushort_t* A0 = As + w * 512;
  ushort_t* A1 = As + 2048 + w * 512;
  const ushort_t* Asrc = Tmb + ((size_t)b * NC + m0 + srow) * NT + koff;
  const int kg = tid >> 5, ng = (tid & 31) * 4;
  f32x4 acc[4][4] = {};
  const int fr = lane & 15, kq = (lane >> 4) * 8;
  for (int k0 = 0; k0 < NT; k0 += 32) {
    glds16(Asrc + k0, A0);
    glds16(Asrc + (size_t)64 * NT + k0, A1);
#pragma unroll
    for (int i = 0; i < 4; i++) {
      int hj = k0 + kg * 4 + i;
      int prow = ((hj >> 6) << 7) + (hj & 63);
      ushort4_t v = *(const ushort4_t*)(P + ((size_t)b * NP + prow) * NN + n0 + ng);
#pragma unroll
      for (int jj = 0; jj < 4; jj++) Bs[(ng + jj) * 40 + kg * 4 + i] = v[jj];
    }
    __syncthreads();
    bf16x8 af[4], bf[4];
#pragma unroll
    for (int f = 0; f < 4; f++) {
      af[f] = *(const bf16x8*)&As[(wm + f * 16 + fr) * 32 + kq];
      bf[f] = *(const bf16x8*)&Bs[(wn + f * 16 + fr) * 40 + kq];
    }
#pragma unroll
    for (int fm = 0; fm < 4; fm++)
#pragma unroll
      for (int fn = 0; fn < 4; fn++) acc[fm][fn] = mfma16(af[fm], bf[fn], acc[fm][fn]);
    __syncthreads();
  }
  const float al = alpha[0];
  const int col = lane & 15, rb = (lane >> 4) * 4;
#pragma unroll
  for (int fm = 0; fm < 4; fm++)
#pragma unroll
    for (int rg = 0; rg < 4; rg++) {
      int row = m0 + wm + fm * 16 + rb + rg;
      float bias = bout[row];
#pragma unroll
      for (int fn = 0; fn < 4; fn++) {
        int cc = n0 + wn + fn * 16 + col;
        size_t idx = ((size_t)b * NC + row) * NN + cc;
        out[idx] = x[idx] + al * (acc[fm][fn][rg] + bias);
      }
    }
}

// ---------------------------------------------------------------------------
extern "C" void kernel_launch(void* const* d_in, const int* in_sizes, int n_in,
                              void* d_out, int out_size, void* d_ws, size_t ws_size,
                              hipStream_t stream) {
  const float* x = (const float*)d_in[0];
  const float* Wqkv = (const float*)d_in[1];
  const float* bqkv = (const float*)d_in[2];
  const float* Wr = (const float*)d_in[3];
  const float* br = (const float*)d_in[4];
  const float* Wout = (const float*)d_in[5];
  const float* bout = (const float*)d_in[6];
  const float* alpha = (const float*)d_in[7];
  float* out = (float*)d_out;

  char* ws = (char*)d_ws;
  ushort_t* P = (ushort_t*)ws;                    // [0, 134217728)
  ushort_t* xb = (ushort_t*)(ws + 134217728);     // 33.5MB (dead after k3)
  ushort_t* XRbT = (ushort_t*)(ws + 134217728);   //   aliases xb: 8.4MB (k3r+)
  ushort_t* xt = (ushort_t*)(ws + 167772160);     // 33.5MB (dead after k1)
  float* XR4 = (float*)(ws + 167772160);          //   aliases xt: 33.5MB
  ushort_t* QKVRb = (ushort_t*)(ws + 167772160);  //   aliases XR4: 25.2MB (k4a+)
  ushort_t* Wrb = (ushort_t*)(ws + 201326592);    // 0.5MB
  float* sPpart = (float*)(ws + 201850880);       // 4.2MB (dead after k2r)
  ushort_t* Wqkvb = (ushort_t*)(ws + 201850880);  //   aliases sPpart: 0.4MB
  float* sP = (float*)(ws + 206045184);           // 64KB
  ushort_t* Tmb = (ushort_t*)(ws + 206110720);    // 4.2MB -> end 210305024

  k0_cvt<<<dim3(64, 4, 16), 256, 0, stream>>>(x, xb, xt);
  cvt_f2b_k<<<256, 256, 0, stream>>>(Wr, Wrb);
  k1_proj<<<4096, 256, 0, stream>>>(Wrb, xt, br, P);
  k2_softmax<<<dim3(64, 16), 512, 0, stream>>>(P, sPpart);
  k2r_reduce<<<64, 256, 0, stream>>>(sPpart, sP);
  cvt_f2b_k<<<192, 256, 0, stream>>>(Wqkv, Wqkvb);  // after k2r (aliases sPpart)
  k3_pool<<<512, 256, 0, stream>>>(xb, P, XR4);
  k3r_tr<<<dim3(16, 4, 16), 256, 0, stream>>>(XR4, XRbT);  // after k3 (aliases xb)
  k4a_qkvr<<<768, 256, 0, stream>>>(Wqkvb, XRbT, bqkv, sP, QKVRb);
  k4b_attn<<<128, 256, 0, stream>>>(QKVRb, Wout, Tmb);
  k5_out<<<1024, 256, 0, stream>>>(x, P, Tmb, bout, alpha, out);
}